// Round 1
// baseline (7760.346 us; speedup 1.0000x reference)
//
#include <hip/hip_runtime.h>

#define N_NODES 50000
#define N_EDGES 800000
#define DIN 128
#define DH   256
#define DOUT 128
#define EPSV 1e-5f
#define SLOPE 0.01f

// ---------------- degree / dinv ----------------
__global__ void deg_kernel(const int* __restrict__ dst, float* __restrict__ deg) {
    int i = blockIdx.x * blockDim.x + threadIdx.x;
    if (i < N_EDGES) atomicAdd(&deg[dst[i]], 1.0f);
}

__global__ void dinv_kernel(float* __restrict__ deg) {
    int i = blockIdx.x * blockDim.x + threadIdx.x;
    if (i < N_NODES) deg[i] = rsqrtf(deg[i] + 1.0f);  // +1 self-loop
}

// ---------------- fp32 GEMM: C[M x Nc] = A[M x K] @ W[Nc x K]^T ----------------
template<int K>
__global__ __launch_bounds__(256) void gemm_awt(const float* __restrict__ A,
                                                const float* __restrict__ W,
                                                float* __restrict__ C,
                                                int M, int Nc) {
    __shared__ float As[64][17];  // +1 pad: kill bank conflicts
    __shared__ float Bs[64][17];
    const int tid = threadIdx.x;
    const int tx = tid & 15, ty = tid >> 4;     // 16x16 thread grid, 4x4 micro-tile
    const int bm = blockIdx.x, bn = blockIdx.y;
    const int lr = tid >> 2, lq = tid & 3;      // load: row 0..63, float4-quad 0..3
    const int arow = bm * 64 + lr;
    const int brow = bn * 64 + lr;
    float acc[4][4] = {};

    for (int kt = 0; kt < K; kt += 16) {
        float4 av = make_float4(0.f, 0.f, 0.f, 0.f);
        if (arow < M) av = *(const float4*)(A + (long)arow * K + kt + lq * 4);
        float4 bv = *(const float4*)(W + (long)brow * K + kt + lq * 4);
        As[lr][lq*4+0] = av.x; As[lr][lq*4+1] = av.y; As[lr][lq*4+2] = av.z; As[lr][lq*4+3] = av.w;
        Bs[lr][lq*4+0] = bv.x; Bs[lr][lq*4+1] = bv.y; Bs[lr][lq*4+2] = bv.z; Bs[lr][lq*4+3] = bv.w;
        __syncthreads();
        #pragma unroll
        for (int k = 0; k < 16; ++k) {
            float a0 = As[ty*4+0][k], a1 = As[ty*4+1][k], a2 = As[ty*4+2][k], a3 = As[ty*4+3][k];
            float b0 = Bs[tx*4+0][k], b1 = Bs[tx*4+1][k], b2 = Bs[tx*4+2][k], b3 = Bs[tx*4+3][k];
            acc[0][0] += a0*b0; acc[0][1] += a0*b1; acc[0][2] += a0*b2; acc[0][3] += a0*b3;
            acc[1][0] += a1*b0; acc[1][1] += a1*b1; acc[1][2] += a1*b2; acc[1][3] += a1*b3;
            acc[2][0] += a2*b0; acc[2][1] += a2*b1; acc[2][2] += a2*b2; acc[2][3] += a2*b3;
            acc[3][0] += a3*b0; acc[3][1] += a3*b1; acc[3][2] += a3*b2; acc[3][3] += a3*b3;
        }
        __syncthreads();
    }
    #pragma unroll
    for (int i = 0; i < 4; ++i) {
        int row = bm * 64 + ty * 4 + i;
        if (row < M) {
            float4 v = make_float4(acc[i][0], acc[i][1], acc[i][2], acc[i][3]);
            *(float4*)(C + (long)row * Nc + bn * 64 + tx * 4) = v;
        }
    }
}

// ---------------- aggregation: out[dst] += enorm * h[src], incl. self-loops ----------------
// one thread per (edge, float4-chunk); out must be pre-zeroed
template<int C4>  // C4 = C/4
__global__ void aggregate_kernel(const int* __restrict__ ei,
                                 const float* __restrict__ dinv,
                                 const float* __restrict__ h,
                                 float* __restrict__ out) {
    const long total = (long)(N_EDGES + N_NODES) * C4;
    const long stride = (long)gridDim.x * blockDim.x;
    for (long idx = (long)blockIdx.x * blockDim.x + threadIdx.x; idx < total; idx += stride) {
        int e = (int)(idx / C4);
        int c = (int)(idx % C4);
        int src, dst; float w;
        if (e < N_EDGES) {
            src = ei[e]; dst = ei[N_EDGES + e];
            w = dinv[src] * dinv[dst];
        } else {
            src = dst = e - N_EDGES;
            float d = dinv[src];
            w = d * d;
        }
        float4 v = ((const float4*)h)[(long)src * C4 + c];
        float* o = out + (long)dst * (C4 * 4) + c * 4;
        atomicAdd(o + 0, v.x * w);
        atomicAdd(o + 1, v.y * w);
        atomicAdd(o + 2, v.z * w);
        atomicAdd(o + 3, v.w * w);
    }
}

// ---------------- BatchNorm stats: stats[0..C-1]=sum, stats[C..2C-1]=sumsq ----------------
template<int C>
__global__ void bn_stats(const float* __restrict__ h, float* __restrict__ stats) {
    constexpr int RPI = 256 / C;            // rows per block-iter
    const int c   = threadIdx.x % C;
    const int rof = threadIdx.x / C;
    float s = 0.f, s2 = 0.f;
    for (int r = blockIdx.x * RPI + rof; r < N_NODES; r += gridDim.x * RPI) {
        float v = h[(long)r * C + c];
        s += v; s2 += v * v;
    }
    atomicAdd(&stats[c], s);
    atomicAdd(&stats[C + c], s2);
}

// ---------------- BN apply (+ optional leaky relu), in-place ----------------
template<int C, bool RELU>
__global__ void bn_apply(float* __restrict__ h, const float* __restrict__ stats,
                         const float* __restrict__ g, const float* __restrict__ be) {
    const long total = (long)N_NODES * C;
    const long stride = (long)gridDim.x * blockDim.x;
    const float invn = 1.0f / (float)N_NODES;
    for (long idx = (long)blockIdx.x * blockDim.x + threadIdx.x; idx < total; idx += stride) {
        int c = (int)(idx % C);
        float mean = stats[c] * invn;
        float var  = stats[C + c] * invn - mean * mean;
        float rstd = rsqrtf(var + EPSV);
        float v = (h[idx] - mean) * rstd * g[c] + be[c];
        if (RELU) v = v > 0.f ? v : SLOPE * v;
        h[idx] = v;
    }
}

extern "C" void kernel_launch(void* const* d_in, const int* in_sizes, int n_in,
                              void* d_out, int out_size, void* d_ws, size_t ws_size,
                              hipStream_t stream) {
    const float* x   = (const float*)d_in[0];
    const int*   ei  = (const int*)  d_in[1];
    const float* W0  = (const float*)d_in[2];
    const float* g0  = (const float*)d_in[4];
    const float* be0 = (const float*)d_in[5];
    const float* W1  = (const float*)d_in[6];
    const float* g1  = (const float*)d_in[8];
    const float* be1 = (const float*)d_in[9];
    const float* W2  = (const float*)d_in[10];
    const float* g2  = (const float*)d_in[12];
    const float* be2 = (const float*)d_in[13];
    float* out = (float*)d_out;

    float* ws    = (float*)d_ws;
    float* dinv  = ws;                                  // N
    float* stats = ws + N_NODES;                        // 2*DH
    float* bufA  = stats + 2 * DH;                      // N*DH (16B-aligned: offset 50512 floats)
    float* bufB  = bufA + (long)N_NODES * DH;           // N*DH

    // degree -> dinv
    hipMemsetAsync(dinv, 0, N_NODES * sizeof(float), stream);
    deg_kernel<<<(N_EDGES + 255) / 256, 256, 0, stream>>>(ei + N_EDGES, dinv);
    dinv_kernel<<<(N_NODES + 255) / 256, 256, 0, stream>>>(dinv);

    dim3 gemm_blk(256);
    // ---- layer 0: x[N,128] @ W0^T -> bufA[N,256]; agg -> bufB; BN+lrelu ----
    gemm_awt<DIN><<<dim3((N_NODES + 63) / 64, DH / 64), gemm_blk, 0, stream>>>(x, W0, bufA, N_NODES, DH);
    hipMemsetAsync(bufB, 0, (size_t)N_NODES * DH * sizeof(float), stream);
    aggregate_kernel<DH / 4><<<2048, 256, 0, stream>>>(ei, dinv, bufA, bufB);
    hipMemsetAsync(stats, 0, 2 * DH * sizeof(float), stream);
    bn_stats<DH><<<1024, 256, 0, stream>>>(bufB, stats);
    bn_apply<DH, true><<<2048, 256, 0, stream>>>(bufB, stats, g0, be0);

    // ---- layer 1: bufB[N,256] @ W1^T -> bufA[N,256]; agg -> bufB; BN+lrelu ----
    gemm_awt<DH><<<dim3((N_NODES + 63) / 64, DH / 64), gemm_blk, 0, stream>>>(bufB, W1, bufA, N_NODES, DH);
    hipMemsetAsync(bufB, 0, (size_t)N_NODES * DH * sizeof(float), stream);
    aggregate_kernel<DH / 4><<<2048, 256, 0, stream>>>(ei, dinv, bufA, bufB);
    hipMemsetAsync(stats, 0, 2 * DH * sizeof(float), stream);
    bn_stats<DH><<<1024, 256, 0, stream>>>(bufB, stats);
    bn_apply<DH, true><<<2048, 256, 0, stream>>>(bufB, stats, g1, be1);

    // ---- layer 2: bufB[N,256] @ W2^T -> bufA[N,128]; agg -> out; BN (no relu) ----
    gemm_awt<DH><<<dim3((N_NODES + 63) / 64, DOUT / 64), gemm_blk, 0, stream>>>(bufB, W2, bufA, N_NODES, DOUT);
    hipMemsetAsync(out, 0, (size_t)N_NODES * DOUT * sizeof(float), stream);
    aggregate_kernel<DOUT / 4><<<2048, 256, 0, stream>>>(ei, dinv, bufA, out);
    hipMemsetAsync(stats, 0, 2 * DH * sizeof(float), stream);
    bn_stats<DOUT><<<1024, 256, 0, stream>>>(out, stats);
    bn_apply<DOUT, false><<<2048, 256, 0, stream>>>(out, stats, g2, be2);
}

// Round 2
// 967.196 us; speedup vs baseline: 8.0236x; 8.0236x over previous
//
#include <hip/hip_runtime.h>

#define N_NODES 50000
#define N_EDGES 800000
#define DIN 128
#define DH   256
#define DOUT 128
#define EPSV 1e-5f
#define SLOPE 0.01f

// ---------------- degree histogram (dst, real edges only) ----------------
__global__ void deg_kernel(const int* __restrict__ dst, int* __restrict__ deg) {
    int i = blockIdx.x * blockDim.x + threadIdx.x;
    if (i < N_EDGES) atomicAdd(&deg[dst[i]], 1);
}

__global__ void dinv_kernel(const int* __restrict__ deg, float* __restrict__ dinv) {
    int i = blockIdx.x * blockDim.x + threadIdx.x;
    if (i < N_NODES) dinv[i] = rsqrtf((float)deg[i] + 1.0f);  // +1 self-loop
}

// ---------------- exclusive scan of (deg+1) -> row_ptr, single block ----------------
__global__ __launch_bounds__(1024) void scan_kernel(const int* __restrict__ deg,
                                                    int* __restrict__ rp) {
    __shared__ int tsum[1024];
    const int t = threadIdx.x;
    const int CH = (N_NODES + 1023) / 1024;  // 49
    const int base = t * CH;
    int s = 0;
    for (int i = 0; i < CH; ++i) {
        int idx = base + i;
        if (idx < N_NODES) s += deg[idx] + 1;
    }
    tsum[t] = s;
    __syncthreads();
    // Hillis-Steele inclusive scan
    for (int off = 1; off < 1024; off <<= 1) {
        int v = tsum[t];
        int add = (t >= off) ? tsum[t - off] : 0;
        __syncthreads();
        tsum[t] = v + add;
        __syncthreads();
    }
    int run = (t == 0) ? 0 : tsum[t - 1];
    for (int i = 0; i < CH; ++i) {
        int idx = base + i;
        if (idx < N_NODES) { rp[idx] = run; run += deg[idx] + 1; }
    }
    if (t == 1023) rp[N_NODES] = tsum[1023];
}

// ---------------- scatter edges (+self loops) into CSR ----------------
__global__ void scatter_kernel(const int* __restrict__ ei, const float* __restrict__ dinv,
                               const int* __restrict__ rp, int* __restrict__ cursor,
                               int* __restrict__ csr_src, float* __restrict__ csr_w) {
    int e = blockIdx.x * blockDim.x + threadIdx.x;
    if (e >= N_EDGES + N_NODES) return;
    int src, dst; float w;
    if (e < N_EDGES) {
        src = ei[e]; dst = ei[N_EDGES + e];
        w = dinv[src] * dinv[dst];
    } else {
        src = dst = e - N_EDGES;
        w = dinv[src] * dinv[src];
    }
    int pos = rp[dst] + atomicAdd(&cursor[dst], 1);
    csr_src[pos] = src;
    csr_w[pos] = w;
}

// ---------------- SpMM: out[r] = sum_e w[e] * h[src[e]]  (atomic-free) ----------------
// C4 lanes per row (C4 float4 chunks = C floats); 256/C4 rows per block
template<int C4>
__global__ __launch_bounds__(256) void spmm_csr(const int* __restrict__ rp,
                                                const int* __restrict__ ci,
                                                const float* __restrict__ cw,
                                                const float* __restrict__ h,
                                                float* __restrict__ out) {
    constexpr int RPB = 256 / C4;
    const int r = blockIdx.x * RPB + threadIdx.x / C4;
    const int l = threadIdx.x % C4;
    if (r >= N_NODES) return;
    const float4* __restrict__ h4 = (const float4*)h;
    const int e0 = rp[r], e1 = rp[r + 1];
    float4 a0 = make_float4(0.f, 0.f, 0.f, 0.f);
    float4 a1 = make_float4(0.f, 0.f, 0.f, 0.f);
    int e = e0;
    for (; e + 2 <= e1; e += 2) {
        int s0 = ci[e], s1 = ci[e + 1];
        float w0 = cw[e], w1 = cw[e + 1];
        float4 v0 = h4[(long)s0 * C4 + l];
        float4 v1 = h4[(long)s1 * C4 + l];
        a0.x = fmaf(w0, v0.x, a0.x); a0.y = fmaf(w0, v0.y, a0.y);
        a0.z = fmaf(w0, v0.z, a0.z); a0.w = fmaf(w0, v0.w, a0.w);
        a1.x = fmaf(w1, v1.x, a1.x); a1.y = fmaf(w1, v1.y, a1.y);
        a1.z = fmaf(w1, v1.z, a1.z); a1.w = fmaf(w1, v1.w, a1.w);
    }
    if (e < e1) {
        int s0 = ci[e]; float w0 = cw[e];
        float4 v0 = h4[(long)s0 * C4 + l];
        a0.x = fmaf(w0, v0.x, a0.x); a0.y = fmaf(w0, v0.y, a0.y);
        a0.z = fmaf(w0, v0.z, a0.z); a0.w = fmaf(w0, v0.w, a0.w);
    }
    float4 res = make_float4(a0.x + a1.x, a0.y + a1.y, a0.z + a1.z, a0.w + a1.w);
    ((float4*)out)[(long)r * C4 + l] = res;
}

// ---------------- fp32 GEMM: C[M x Nc] = A[M x K] @ W[Nc x K]^T ----------------
template<int K>
__global__ __launch_bounds__(256) void gemm_awt(const float* __restrict__ A,
                                                const float* __restrict__ W,
                                                float* __restrict__ C,
                                                int M, int Nc) {
    __shared__ float As[64][17];
    __shared__ float Bs[64][17];
    const int tid = threadIdx.x;
    const int tx = tid & 15, ty = tid >> 4;
    const int bm = blockIdx.x, bn = blockIdx.y;
    const int lr = tid >> 2, lq = tid & 3;
    const int arow = bm * 64 + lr;
    const int brow = bn * 64 + lr;
    float acc[4][4] = {};

    for (int kt = 0; kt < K; kt += 16) {
        float4 av = make_float4(0.f, 0.f, 0.f, 0.f);
        if (arow < M) av = *(const float4*)(A + (long)arow * K + kt + lq * 4);
        float4 bv = *(const float4*)(W + (long)brow * K + kt + lq * 4);
        As[lr][lq*4+0] = av.x; As[lr][lq*4+1] = av.y; As[lr][lq*4+2] = av.z; As[lr][lq*4+3] = av.w;
        Bs[lr][lq*4+0] = bv.x; Bs[lr][lq*4+1] = bv.y; Bs[lr][lq*4+2] = bv.z; Bs[lr][lq*4+3] = bv.w;
        __syncthreads();
        #pragma unroll
        for (int k = 0; k < 16; ++k) {
            float a0 = As[ty*4+0][k], a1 = As[ty*4+1][k], a2 = As[ty*4+2][k], a3 = As[ty*4+3][k];
            float b0 = Bs[tx*4+0][k], b1 = Bs[tx*4+1][k], b2 = Bs[tx*4+2][k], b3 = Bs[tx*4+3][k];
            acc[0][0] += a0*b0; acc[0][1] += a0*b1; acc[0][2] += a0*b2; acc[0][3] += a0*b3;
            acc[1][0] += a1*b0; acc[1][1] += a1*b1; acc[1][2] += a1*b2; acc[1][3] += a1*b3;
            acc[2][0] += a2*b0; acc[2][1] += a2*b1; acc[2][2] += a2*b2; acc[2][3] += a2*b3;
            acc[3][0] += a3*b0; acc[3][1] += a3*b1; acc[3][2] += a3*b2; acc[3][3] += a3*b3;
        }
        __syncthreads();
    }
    #pragma unroll
    for (int i = 0; i < 4; ++i) {
        int row = bm * 64 + ty * 4 + i;
        if (row < M) {
            float4 v = make_float4(acc[i][0], acc[i][1], acc[i][2], acc[i][3]);
            *(float4*)(C + (long)row * Nc + bn * 64 + tx * 4) = v;
        }
    }
}

// ---------------- BatchNorm stats: stats[0..C-1]=sum, stats[C..2C-1]=sumsq ----------------
template<int C>
__global__ void bn_stats(const float* __restrict__ h, float* __restrict__ stats) {
    constexpr int RPI = 256 / C;
    const int c   = threadIdx.x % C;
    const int rof = threadIdx.x / C;
    float s = 0.f, s2 = 0.f;
    for (int r = blockIdx.x * RPI + rof; r < N_NODES; r += gridDim.x * RPI) {
        float v = h[(long)r * C + c];
        s += v; s2 += v * v;
    }
    atomicAdd(&stats[c], s);
    atomicAdd(&stats[C + c], s2);
}

// ---------------- BN apply (+ optional leaky relu), in-place ----------------
template<int C, bool RELU>
__global__ void bn_apply(float* __restrict__ h, const float* __restrict__ stats,
                         const float* __restrict__ g, const float* __restrict__ be) {
    const long total = (long)N_NODES * C;
    const long stride = (long)gridDim.x * blockDim.x;
    const float invn = 1.0f / (float)N_NODES;
    for (long idx = (long)blockIdx.x * blockDim.x + threadIdx.x; idx < total; idx += stride) {
        int c = (int)(idx % C);
        float mean = stats[c] * invn;
        float var  = stats[C + c] * invn - mean * mean;
        float rstd = rsqrtf(var + EPSV);
        float v = (h[idx] - mean) * rstd * g[c] + be[c];
        if (RELU) v = v > 0.f ? v : SLOPE * v;
        h[idx] = v;
    }
}

extern "C" void kernel_launch(void* const* d_in, const int* in_sizes, int n_in,
                              void* d_out, int out_size, void* d_ws, size_t ws_size,
                              hipStream_t stream) {
    const float* x   = (const float*)d_in[0];
    const int*   ei  = (const int*)  d_in[1];
    const float* W0  = (const float*)d_in[2];
    const float* g0  = (const float*)d_in[4];
    const float* be0 = (const float*)d_in[5];
    const float* W1  = (const float*)d_in[6];
    const float* g1  = (const float*)d_in[8];
    const float* be1 = (const float*)d_in[9];
    const float* W2  = (const float*)d_in[10];
    const float* g2  = (const float*)d_in[12];
    const float* be2 = (const float*)d_in[13];
    float* out = (float*)d_out;

    // workspace layout (all 16B-aligned)
    char* wsb = (char*)d_ws;
    int*   deg     = (int*)wsb;                       wsb += 50000 * 4;
    int*   rp      = (int*)wsb;                       wsb += 50004 * 4;   // N+1, padded
    int*   cursor  = (int*)wsb;                       wsb += 50000 * 4;
    float* dinv    = (float*)wsb;                     wsb += 50000 * 4;
    float* stats   = (float*)wsb;                     wsb += 512 * 4;
    int*   csr_src = (int*)wsb;                       wsb += 850000 * 4;
    float* csr_w   = (float*)wsb;                     wsb += 850000 * 4;
    float* bufA    = (float*)wsb;                     wsb += (size_t)N_NODES * DH * 4;
    float* bufB    = (float*)wsb;

    // ---- CSR build ----
    hipMemsetAsync(deg, 0, 50000 * 4, stream);
    hipMemsetAsync(cursor, 0, 50000 * 4, stream);
    deg_kernel<<<(N_EDGES + 255) / 256, 256, 0, stream>>>(ei + N_EDGES, deg);
    dinv_kernel<<<(N_NODES + 255) / 256, 256, 0, stream>>>(deg, dinv);
    scan_kernel<<<1, 1024, 0, stream>>>(deg, rp);
    scatter_kernel<<<(N_EDGES + N_NODES + 255) / 256, 256, 0, stream>>>(
        ei, dinv, rp, cursor, csr_src, csr_w);

    dim3 gemm_blk(256);
    // ---- layer 0: aggregate x (DIN=128) FIRST: A(XW^T) = (AX)W^T ----
    spmm_csr<DIN / 4><<<(N_NODES * (DIN / 4) + 255) / 256, 256, 0, stream>>>(
        rp, csr_src, csr_w, x, bufA);
    gemm_awt<DIN><<<dim3((N_NODES + 63) / 64, DH / 64), gemm_blk, 0, stream>>>(
        bufA, W0, bufB, N_NODES, DH);
    hipMemsetAsync(stats, 0, 2 * DH * 4, stream);
    bn_stats<DH><<<1024, 256, 0, stream>>>(bufB, stats);
    bn_apply<DH, true><<<2048, 256, 0, stream>>>(bufB, stats, g0, be0);

    // ---- layer 1: gemm then aggregate (DH=256) ----
    gemm_awt<DH><<<dim3((N_NODES + 63) / 64, DH / 64), gemm_blk, 0, stream>>>(
        bufB, W1, bufA, N_NODES, DH);
    spmm_csr<DH / 4><<<(N_NODES * (DH / 4) + 255) / 256, 256, 0, stream>>>(
        rp, csr_src, csr_w, bufA, bufB);
    hipMemsetAsync(stats, 0, 2 * DH * 4, stream);
    bn_stats<DH><<<1024, 256, 0, stream>>>(bufB, stats);
    bn_apply<DH, true><<<2048, 256, 0, stream>>>(bufB, stats, g1, be1);

    // ---- layer 2: gemm (DOUT=128) then aggregate into out ----
    gemm_awt<DH><<<dim3((N_NODES + 63) / 64, DOUT / 64), gemm_blk, 0, stream>>>(
        bufB, W2, bufA, N_NODES, DOUT);
    spmm_csr<DOUT / 4><<<(N_NODES * (DOUT / 4) + 255) / 256, 256, 0, stream>>>(
        rp, csr_src, csr_w, bufA, out);
    hipMemsetAsync(stats, 0, 2 * DH * 4, stream);
    bn_stats<DOUT><<<1024, 256, 0, stream>>>(out, stats);
    bn_apply<DOUT, false><<<2048, 256, 0, stream>>>(out, stats, g2, be2);
}

// Round 3
// 588.908 us; speedup vs baseline: 13.1775x; 1.6424x over previous
//
#include <hip/hip_runtime.h>
#include <hip/hip_bf16.h>

#define N_NODES 50000
#define N_EDGES 800000
#define DIN 128
#define DH   256
#define DOUT 128
#define EPSV 1e-5f
#define SLOPE 0.01f

typedef __bf16 bf16x8 __attribute__((ext_vector_type(8)));
typedef __bf16 bf16x4 __attribute__((ext_vector_type(4)));
typedef float  f32x4  __attribute__((ext_vector_type(4)));

// ---------------- weight cast f32 -> bf16 ----------------
__global__ void cast_kernel(const float* __restrict__ src, __bf16* __restrict__ dst, int n4) {
    int i = blockIdx.x * blockDim.x + threadIdx.x;
    if (i < n4) {
        float4 v = ((const float4*)src)[i];
        bf16x4 o; o[0] = (__bf16)v.x; o[1] = (__bf16)v.y; o[2] = (__bf16)v.z; o[3] = (__bf16)v.w;
        ((bf16x4*)dst)[i] = o;
    }
}

// ---------------- CSR build ----------------
__global__ void deg_kernel(const int* __restrict__ dst, int* __restrict__ deg) {
    int i = blockIdx.x * blockDim.x + threadIdx.x;
    if (i < N_EDGES) atomicAdd(&deg[dst[i]], 1);
}

__global__ void dinv_kernel(const int* __restrict__ deg, float* __restrict__ dinv) {
    int i = blockIdx.x * blockDim.x + threadIdx.x;
    if (i < N_NODES) dinv[i] = rsqrtf((float)deg[i] + 1.0f);  // +1 self-loop
}

__global__ __launch_bounds__(1024) void scan_kernel(const int* __restrict__ deg,
                                                    int* __restrict__ rp) {
    __shared__ int tsum[1024];
    const int t = threadIdx.x;
    const int CH = (N_NODES + 1023) / 1024;  // 49
    const int base = t * CH;
    int s = 0;
    for (int i = 0; i < CH; ++i) {
        int idx = base + i;
        if (idx < N_NODES) s += deg[idx] + 1;
    }
    tsum[t] = s;
    __syncthreads();
    for (int off = 1; off < 1024; off <<= 1) {
        int v = tsum[t];
        int add = (t >= off) ? tsum[t - off] : 0;
        __syncthreads();
        tsum[t] = v + add;
        __syncthreads();
    }
    int run = (t == 0) ? 0 : tsum[t - 1];
    for (int i = 0; i < CH; ++i) {
        int idx = base + i;
        if (idx < N_NODES) { rp[idx] = run; run += deg[idx] + 1; }
    }
    if (t == 1023) rp[N_NODES] = tsum[1023];
}

__global__ void scatter_kernel(const int* __restrict__ ei, const float* __restrict__ dinv,
                               const int* __restrict__ rp, int* __restrict__ cursor,
                               int* __restrict__ csr_src, float* __restrict__ csr_w) {
    int e = blockIdx.x * blockDim.x + threadIdx.x;
    if (e >= N_EDGES + N_NODES) return;
    int src, dst; float w;
    if (e < N_EDGES) {
        src = ei[e]; dst = ei[N_EDGES + e];
        w = dinv[src] * dinv[dst];
    } else {
        src = dst = e - N_EDGES;
        w = dinv[src] * dinv[src];
    }
    int pos = rp[dst] + atomicAdd(&cursor[dst], 1);
    csr_src[pos] = src;
    csr_w[pos] = w;
}

// ---------------- SpMM: f32 in -> bf16 out (layer 0, C=128) ----------------
template<int C4>  // lanes per row, 4 floats each
__global__ __launch_bounds__(256) void spmm_f2b(const int* __restrict__ rp,
                                                const int* __restrict__ ci,
                                                const float* __restrict__ cw,
                                                const float* __restrict__ h,
                                                __bf16* __restrict__ out) {
    constexpr int C = C4 * 4;
    constexpr int RPB = 256 / C4;
    const int r = blockIdx.x * RPB + threadIdx.x / C4;
    const int l = threadIdx.x % C4;
    if (r >= N_NODES) return;
    const float4* __restrict__ h4 = (const float4*)h;
    const int e0 = rp[r], e1 = rp[r + 1];
    f32x4 a0 = {0.f, 0.f, 0.f, 0.f}, a1 = {0.f, 0.f, 0.f, 0.f};
    int e = e0;
    for (; e + 2 <= e1; e += 2) {
        int s0 = ci[e], s1 = ci[e + 1];
        float w0 = cw[e], w1 = cw[e + 1];
        float4 v0 = h4[(long)s0 * C4 + l];
        float4 v1 = h4[(long)s1 * C4 + l];
        a0[0] = fmaf(w0, v0.x, a0[0]); a0[1] = fmaf(w0, v0.y, a0[1]);
        a0[2] = fmaf(w0, v0.z, a0[2]); a0[3] = fmaf(w0, v0.w, a0[3]);
        a1[0] = fmaf(w1, v1.x, a1[0]); a1[1] = fmaf(w1, v1.y, a1[1]);
        a1[2] = fmaf(w1, v1.z, a1[2]); a1[3] = fmaf(w1, v1.w, a1[3]);
    }
    if (e < e1) {
        int s0 = ci[e]; float w0 = cw[e];
        float4 v0 = h4[(long)s0 * C4 + l];
        a0[0] = fmaf(w0, v0.x, a0[0]); a0[1] = fmaf(w0, v0.y, a0[1]);
        a0[2] = fmaf(w0, v0.z, a0[2]); a0[3] = fmaf(w0, v0.w, a0[3]);
    }
    bf16x4 res;
    #pragma unroll
    for (int j = 0; j < 4; ++j) res[j] = (__bf16)(a0[j] + a1[j]);
    ((bf16x4*)out)[(long)r * C4 + l] = res;
}

// ---------------- SpMM: bf16 in -> bf16/f32 out ----------------
template<int C8, bool OUTF32>  // lanes per row, 8 bf16 each
__global__ __launch_bounds__(256) void spmm_b(const int* __restrict__ rp,
                                              const int* __restrict__ ci,
                                              const float* __restrict__ cw,
                                              const __bf16* __restrict__ h,
                                              void* __restrict__ outp) {
    constexpr int C = C8 * 8;
    constexpr int RPB = 256 / C8;
    const int r = blockIdx.x * RPB + threadIdx.x / C8;
    const int l = threadIdx.x % C8;
    if (r >= N_NODES) return;
    const bf16x8* __restrict__ h8 = (const bf16x8*)h;
    const int e0 = rp[r], e1 = rp[r + 1];
    float acc0[8] = {}, acc1[8] = {};
    int e = e0;
    for (; e + 2 <= e1; e += 2) {
        int s0 = ci[e], s1 = ci[e + 1];
        float w0 = cw[e], w1 = cw[e + 1];
        bf16x8 v0 = h8[(long)s0 * C8 + l];
        bf16x8 v1 = h8[(long)s1 * C8 + l];
        #pragma unroll
        for (int j = 0; j < 8; ++j) {
            acc0[j] = fmaf(w0, (float)v0[j], acc0[j]);
            acc1[j] = fmaf(w1, (float)v1[j], acc1[j]);
        }
    }
    if (e < e1) {
        int s0 = ci[e]; float w0 = cw[e];
        bf16x8 v0 = h8[(long)s0 * C8 + l];
        #pragma unroll
        for (int j = 0; j < 8; ++j) acc0[j] = fmaf(w0, (float)v0[j], acc0[j]);
    }
    if (OUTF32) {
        float* o = (float*)outp + (long)r * C + l * 8;
        float4 r0 = make_float4(acc0[0] + acc1[0], acc0[1] + acc1[1], acc0[2] + acc1[2], acc0[3] + acc1[3]);
        float4 r1 = make_float4(acc0[4] + acc1[4], acc0[5] + acc1[5], acc0[6] + acc1[6], acc0[7] + acc1[7]);
        ((float4*)o)[0] = r0; ((float4*)o)[1] = r1;
    } else {
        bf16x8 res;
        #pragma unroll
        for (int j = 0; j < 8; ++j) res[j] = (__bf16)(acc0[j] + acc1[j]);
        ((bf16x8*)outp)[(long)r * C8 + l] = res;
    }
}

// ---------------- bf16 MFMA GEMM: C[M x Nc](bf16) = A[M x K](bf16) @ W[Nc x K](bf16)^T ----
// block = 4 waves; block tile 64(M) x 64(N); wave owns 64x16
template<int K>
__global__ __launch_bounds__(256) void gemm_mfma(const __bf16* __restrict__ A,
                                                 const __bf16* __restrict__ W,
                                                 __bf16* __restrict__ C,
                                                 int M, int Nc) {
    const int tid = threadIdx.x;
    const int wave = tid >> 6, lane = tid & 63;
    const int ln15 = lane & 15, kg = lane >> 4;       // kg = k-group 0..3
    const int m0 = blockIdx.x * 64;
    const int n0 = blockIdx.y * 64 + wave * 16;
    f32x4 acc[4];
    #pragma unroll
    for (int i = 0; i < 4; ++i) acc[i] = (f32x4){0.f, 0.f, 0.f, 0.f};

    int mrow[4];
    #pragma unroll
    for (int i = 0; i < 4; ++i) {
        int m = m0 + i * 16 + ln15;
        mrow[i] = m < M ? m : M - 1;   // clamp (stores guarded)
    }
    const __bf16* wptr = W + (long)(n0 + ln15) * K + kg * 8;
    for (int kk = 0; kk < K; kk += 32) {
        bf16x8 b = *(const bf16x8*)(wptr + kk);
        #pragma unroll
        for (int i = 0; i < 4; ++i) {
            bf16x8 a = *(const bf16x8*)(A + (long)mrow[i] * K + kk + kg * 8);
            acc[i] = __builtin_amdgcn_mfma_f32_16x16x32_bf16(a, b, acc[i], 0, 0, 0);
        }
    }
    #pragma unroll
    for (int i = 0; i < 4; ++i) {
        #pragma unroll
        for (int j = 0; j < 4; ++j) {
            int r = m0 + i * 16 + kg * 4 + j;   // C/D: row=(lane>>4)*4+reg, col=lane&15
            if (r < M) C[(long)r * Nc + n0 + ln15] = (__bf16)acc[i][j];
        }
    }
}

// ---------------- BN stats: per-block partial sums (atomic-free) ----------------
#define NB_STATS 128
template<int C, bool BF16>
__global__ __launch_bounds__(256) void bn_stats(const void* __restrict__ hp,
                                                float* __restrict__ partial) {
    constexpr int LPR = C / 4;          // lanes per row
    constexpr int RPI = 256 / LPR;      // rows per block-iter
    const int chunk = threadIdx.x % LPR;
    const int rof   = threadIdx.x / LPR;
    float s[4] = {}, s2[4] = {};
    for (int r = blockIdx.x * RPI + rof; r < N_NODES; r += NB_STATS * RPI) {
        float v[4];
        if (BF16) {
            bf16x4 x = ((const bf16x4*)hp)[(long)r * LPR + chunk];
            #pragma unroll
            for (int j = 0; j < 4; ++j) v[j] = (float)x[j];
        } else {
            float4 x = ((const float4*)hp)[(long)r * LPR + chunk];
            v[0] = x.x; v[1] = x.y; v[2] = x.z; v[3] = x.w;
        }
        #pragma unroll
        for (int j = 0; j < 4; ++j) { s[j] += v[j]; s2[j] += v[j] * v[j]; }
    }
    __shared__ float red[256 * 8];
    #pragma unroll
    for (int j = 0; j < 4; ++j) { red[threadIdx.x * 8 + j] = s[j]; red[threadIdx.x * 8 + 4 + j] = s2[j]; }
    __syncthreads();
    if (rof == 0) {
        #pragma unroll
        for (int g = 1; g < RPI; ++g) {
            #pragma unroll
            for (int j = 0; j < 4; ++j) {
                s[j]  += red[(g * LPR + chunk) * 8 + j];
                s2[j] += red[(g * LPR + chunk) * 8 + 4 + j];
            }
        }
        #pragma unroll
        for (int j = 0; j < 4; ++j) {
            partial[blockIdx.x * 2 * C + chunk * 4 + j]     = s[j];
            partial[blockIdx.x * 2 * C + C + chunk * 4 + j] = s2[j];
        }
    }
}

// ---------------- reduce partials -> per-column scale/shift ----------------
template<int C>
__global__ void bn_reduce(const float* __restrict__ partial, const float* __restrict__ g,
                          const float* __restrict__ be, float* __restrict__ ss) {
    int c = threadIdx.x;  // C threads
    float s = 0.f, s2 = 0.f;
    for (int b = 0; b < NB_STATS; ++b) {
        s  += partial[b * 2 * C + c];
        s2 += partial[b * 2 * C + C + c];
    }
    const float invn = 1.0f / (float)N_NODES;
    float mean = s * invn;
    float var  = s2 * invn - mean * mean;
    float rstd = rsqrtf(var + EPSV);
    float sc = g[c] * rstd;
    ss[c] = sc;
    ss[C + c] = be[c] - mean * sc;
}

// ---------------- BN apply (+leaky), vectorized, in-place capable ----------------
template<int C, bool RELU, bool INF32, bool OUTF32>
__global__ __launch_bounds__(256) void bn_apply(const void* __restrict__ in,
                                                void* __restrict__ outp,
                                                const float* __restrict__ ss) {
    constexpr int LPR = C / 4;
    const long total = (long)N_NODES * LPR;
    const long stride = (long)gridDim.x * blockDim.x;
    for (long idx = (long)blockIdx.x * blockDim.x + threadIdx.x; idx < total; idx += stride) {
        int chunk = (int)(idx % LPR);
        float4 sc = ((const float4*)ss)[chunk];
        float4 sh = ((const float4*)(ss + C))[chunk];
        float v[4];
        if (INF32) {
            float4 x = ((const float4*)in)[idx];
            v[0] = x.x; v[1] = x.y; v[2] = x.z; v[3] = x.w;
        } else {
            bf16x4 x = ((const bf16x4*)in)[idx];
            #pragma unroll
            for (int j = 0; j < 4; ++j) v[j] = (float)x[j];
        }
        v[0] = fmaf(v[0], sc.x, sh.x); v[1] = fmaf(v[1], sc.y, sh.y);
        v[2] = fmaf(v[2], sc.z, sh.z); v[3] = fmaf(v[3], sc.w, sh.w);
        if (RELU) {
            #pragma unroll
            for (int j = 0; j < 4; ++j) v[j] = v[j] > 0.f ? v[j] : SLOPE * v[j];
        }
        if (OUTF32) {
            ((float4*)outp)[idx] = make_float4(v[0], v[1], v[2], v[3]);
        } else {
            bf16x4 o;
            #pragma unroll
            for (int j = 0; j < 4; ++j) o[j] = (__bf16)v[j];
            ((bf16x4*)outp)[idx] = o;
        }
    }
}

extern "C" void kernel_launch(void* const* d_in, const int* in_sizes, int n_in,
                              void* d_out, int out_size, void* d_ws, size_t ws_size,
                              hipStream_t stream) {
    const float* x   = (const float*)d_in[0];
    const int*   ei  = (const int*)  d_in[1];
    const float* W0  = (const float*)d_in[2];
    const float* g0  = (const float*)d_in[4];
    const float* be0 = (const float*)d_in[5];
    const float* W1  = (const float*)d_in[6];
    const float* g1  = (const float*)d_in[8];
    const float* be1 = (const float*)d_in[9];
    const float* W2  = (const float*)d_in[10];
    const float* g2  = (const float*)d_in[12];
    const float* be2 = (const float*)d_in[13];
    float* out = (float*)d_out;

    char* wsb = (char*)d_ws;
    auto alloc = [&](size_t bytes) { char* p = wsb; wsb += (bytes + 255) & ~255UL; return p; };
    int*    deg     = (int*)   alloc(N_NODES * 4);
    int*    rp      = (int*)   alloc((N_NODES + 4) * 4);
    int*    cursor  = (int*)   alloc(N_NODES * 4);
    float*  dinv    = (float*) alloc(N_NODES * 4);
    float*  partial = (float*) alloc(NB_STATS * 2 * DH * 4);
    float*  ss      = (float*) alloc(2 * DH * 4);
    int*    csr_src = (int*)   alloc((N_EDGES + N_NODES) * 4);
    float*  csr_w   = (float*) alloc((N_EDGES + N_NODES) * 4);
    __bf16* w0b     = (__bf16*)alloc(DH * DIN * 2);
    __bf16* w1b     = (__bf16*)alloc(DH * DH * 2);
    __bf16* w2b     = (__bf16*)alloc(DOUT * DH * 2);
    __bf16* bf0     = (__bf16*)alloc((size_t)N_NODES * DH * 2);
    __bf16* bf1     = (__bf16*)alloc((size_t)N_NODES * DH * 2);

    // ---- weights -> bf16 ----
    cast_kernel<<<(DH * DIN / 4 + 255) / 256, 256, 0, stream>>>(W0, w0b, DH * DIN / 4);
    cast_kernel<<<(DH * DH  / 4 + 255) / 256, 256, 0, stream>>>(W1, w1b, DH * DH / 4);
    cast_kernel<<<(DOUT * DH / 4 + 255) / 256, 256, 0, stream>>>(W2, w2b, DOUT * DH / 4);

    // ---- CSR build ----
    hipMemsetAsync(deg, 0, N_NODES * 4, stream);
    hipMemsetAsync(cursor, 0, N_NODES * 4, stream);
    deg_kernel<<<(N_EDGES + 255) / 256, 256, 0, stream>>>(ei + N_EDGES, deg);
    dinv_kernel<<<(N_NODES + 255) / 256, 256, 0, stream>>>(deg, dinv);
    scan_kernel<<<1, 1024, 0, stream>>>(deg, rp);
    scatter_kernel<<<(N_EDGES + N_NODES + 255) / 256, 256, 0, stream>>>(
        ei, dinv, rp, cursor, csr_src, csr_w);

    // ---- layer 0: aggregate x first (A(XW^T) = (AX)W^T), DIN=128 ----
    spmm_f2b<DIN / 4><<<(N_NODES + 7) / 8, 256, 0, stream>>>(rp, csr_src, csr_w, x, bf0);
    gemm_mfma<DIN><<<dim3((N_NODES + 63) / 64, DH / 64), 256, 0, stream>>>(bf0, w0b, bf1, N_NODES, DH);
    bn_stats<DH, true><<<NB_STATS, 256, 0, stream>>>(bf1, partial);
    bn_reduce<DH><<<1, DH, 0, stream>>>(partial, g0, be0, ss);
    bn_apply<DH, true, false, false><<<2048, 256, 0, stream>>>(bf1, bf1, ss);

    // ---- layer 1 ----
    gemm_mfma<DH><<<dim3((N_NODES + 63) / 64, DH / 64), 256, 0, stream>>>(bf1, w1b, bf0, N_NODES, DH);
    spmm_b<DH / 8, false><<<(N_NODES + 7) / 8, 256, 0, stream>>>(rp, csr_src, csr_w, bf0, bf1);
    bn_stats<DH, true><<<NB_STATS, 256, 0, stream>>>(bf1, partial);
    bn_reduce<DH><<<1, DH, 0, stream>>>(partial, g1, be1, ss);
    bn_apply<DH, true, false, false><<<2048, 256, 0, stream>>>(bf1, bf1, ss);

    // ---- layer 2 ----
    gemm_mfma<DH><<<dim3((N_NODES + 63) / 64, DOUT / 64), 256, 0, stream>>>(bf1, w2b, bf0, N_NODES, DOUT);
    spmm_b<DOUT / 8, true><<<(N_NODES + 15) / 16, 256, 0, stream>>>(rp, csr_src, csr_w, bf0, out);
    bn_stats<DOUT, false><<<NB_STATS, 256, 0, stream>>>(out, partial);
    bn_reduce<DOUT><<<1, DOUT, 0, stream>>>(partial, g2, be2, ss);
    bn_apply<DOUT, false, true, true><<<2048, 256, 0, stream>>>(out, out, ss);
}

// Round 4
// 518.462 us; speedup vs baseline: 14.9680x; 1.1359x over previous
//
#include <hip/hip_runtime.h>
#include <hip/hip_bf16.h>

#define N_NODES 50000
#define N_EDGES 800000
#define DIN 128
#define DH   256
#define DOUT 128
#define EPSV 1e-5f
#define SLOPE 0.01f
#define SCAN_NB ((N_NODES + 255) / 256)   // 196

typedef __bf16 bf16x8 __attribute__((ext_vector_type(8)));
typedef __bf16 bf16x4 __attribute__((ext_vector_type(4)));
typedef float  f32x4  __attribute__((ext_vector_type(4)));

// ---------------- weight cast f32 -> bf16 ----------------
__global__ void cast_kernel(const float* __restrict__ src, __bf16* __restrict__ dst, int n4) {
    int i = blockIdx.x * blockDim.x + threadIdx.x;
    if (i < n4) {
        float4 v = ((const float4*)src)[i];
        bf16x4 o; o[0] = (__bf16)v.x; o[1] = (__bf16)v.y; o[2] = (__bf16)v.z; o[3] = (__bf16)v.w;
        ((bf16x4*)dst)[i] = o;
    }
}

// ---------------- CSR build ----------------
__global__ void deg_kernel(const int* __restrict__ dst, int* __restrict__ deg) {
    int i = blockIdx.x * blockDim.x + threadIdx.x;
    if (i < N_EDGES) atomicAdd(&deg[dst[i]], 1);
}

__global__ void dinv_kernel(const int* __restrict__ deg, float* __restrict__ dinv) {
    int i = blockIdx.x * blockDim.x + threadIdx.x;
    if (i < N_NODES) dinv[i] = rsqrtf((float)deg[i] + 1.0f);  // +1 self-loop
}

// ---- multi-block scan of (deg+1) -> rp ----
__global__ __launch_bounds__(256) void scan_bsum(const int* __restrict__ deg,
                                                 int* __restrict__ bsum) {
    __shared__ int lds[256];
    int i = blockIdx.x * 256 + threadIdx.x;
    lds[threadIdx.x] = (i < N_NODES) ? deg[i] + 1 : 0;
    __syncthreads();
    #pragma unroll
    for (int off = 128; off > 0; off >>= 1) {
        if (threadIdx.x < off) lds[threadIdx.x] += lds[threadIdx.x + off];
        __syncthreads();
    }
    if (threadIdx.x == 0) bsum[blockIdx.x] = lds[0];
}

__global__ __launch_bounds__(256) void scan_boffs(const int* __restrict__ bsum,
                                                  int* __restrict__ boffs) {
    __shared__ int lds[256];
    const int t = threadIdx.x;
    lds[t] = (t < SCAN_NB) ? bsum[t] : 0;
    __syncthreads();
    #pragma unroll
    for (int off = 1; off < 256; off <<= 1) {
        int add = (t >= off) ? lds[t - off] : 0;
        __syncthreads();
        lds[t] += add;
        __syncthreads();
    }
    boffs[t] = (t == 0) ? 0 : lds[t - 1];   // exclusive
}

__global__ __launch_bounds__(256) void scan_write(const int* __restrict__ deg,
                                                  const int* __restrict__ boffs,
                                                  int* __restrict__ rp) {
    __shared__ int lds[256];
    const int t = threadIdx.x;
    int i = blockIdx.x * 256 + t;
    int v = (i < N_NODES) ? deg[i] + 1 : 0;
    lds[t] = v;
    __syncthreads();
    #pragma unroll
    for (int off = 1; off < 256; off <<= 1) {
        int add = (t >= off) ? lds[t - off] : 0;
        __syncthreads();
        lds[t] += add;
        __syncthreads();
    }
    if (i < N_NODES) rp[i] = boffs[blockIdx.x] + lds[t] - v;
    if (i == N_NODES - 1) rp[N_NODES] = boffs[blockIdx.x] + lds[t];
}

__global__ void scatter_kernel(const int* __restrict__ ei, const float* __restrict__ dinv,
                               const int* __restrict__ rp, int* __restrict__ cursor,
                               int* __restrict__ csr_src, float* __restrict__ csr_w) {
    int e = blockIdx.x * blockDim.x + threadIdx.x;
    if (e >= N_EDGES + N_NODES) return;
    int src, dst; float w;
    if (e < N_EDGES) {
        src = ei[e]; dst = ei[N_EDGES + e];
        w = dinv[src] * dinv[dst];
    } else {
        src = dst = e - N_EDGES;
        w = dinv[src] * dinv[src];
    }
    int pos = rp[dst] + atomicAdd(&cursor[dst], 1);
    csr_src[pos] = src;
    csr_w[pos] = w;
}

// ---------------- SpMM: f32 in -> bf16 out (layer 0, C=128) ----------------
template<int C4>
__global__ __launch_bounds__(256) void spmm_f2b(const int* __restrict__ rp,
                                                const int* __restrict__ ci,
                                                const float* __restrict__ cw,
                                                const float* __restrict__ h,
                                                __bf16* __restrict__ out) {
    constexpr int RPB = 256 / C4;
    const int r = blockIdx.x * RPB + threadIdx.x / C4;
    const int l = threadIdx.x % C4;
    if (r >= N_NODES) return;
    const float4* __restrict__ h4 = (const float4*)h;
    const int e0 = rp[r], e1 = rp[r + 1];
    f32x4 a0 = {0.f, 0.f, 0.f, 0.f}, a1 = {0.f, 0.f, 0.f, 0.f};
    int e = e0;
    for (; e + 4 <= e1; e += 4) {
        int s0 = ci[e], s1 = ci[e + 1], s2 = ci[e + 2], s3 = ci[e + 3];
        float w0 = cw[e], w1 = cw[e + 1], w2 = cw[e + 2], w3 = cw[e + 3];
        float4 v0 = h4[(long)s0 * C4 + l];
        float4 v1 = h4[(long)s1 * C4 + l];
        float4 v2 = h4[(long)s2 * C4 + l];
        float4 v3 = h4[(long)s3 * C4 + l];
        a0[0] = fmaf(w0, v0.x, a0[0]); a0[1] = fmaf(w0, v0.y, a0[1]);
        a0[2] = fmaf(w0, v0.z, a0[2]); a0[3] = fmaf(w0, v0.w, a0[3]);
        a1[0] = fmaf(w1, v1.x, a1[0]); a1[1] = fmaf(w1, v1.y, a1[1]);
        a1[2] = fmaf(w1, v1.z, a1[2]); a1[3] = fmaf(w1, v1.w, a1[3]);
        a0[0] = fmaf(w2, v2.x, a0[0]); a0[1] = fmaf(w2, v2.y, a0[1]);
        a0[2] = fmaf(w2, v2.z, a0[2]); a0[3] = fmaf(w2, v2.w, a0[3]);
        a1[0] = fmaf(w3, v3.x, a1[0]); a1[1] = fmaf(w3, v3.y, a1[1]);
        a1[2] = fmaf(w3, v3.z, a1[2]); a1[3] = fmaf(w3, v3.w, a1[3]);
    }
    for (; e < e1; ++e) {
        int s0 = ci[e]; float w0 = cw[e];
        float4 v0 = h4[(long)s0 * C4 + l];
        a0[0] = fmaf(w0, v0.x, a0[0]); a0[1] = fmaf(w0, v0.y, a0[1]);
        a0[2] = fmaf(w0, v0.z, a0[2]); a0[3] = fmaf(w0, v0.w, a0[3]);
    }
    bf16x4 res;
    #pragma unroll
    for (int j = 0; j < 4; ++j) res[j] = (__bf16)(a0[j] + a1[j]);
    ((bf16x4*)out)[(long)r * C4 + l] = res;
}

// ---------------- SpMM: bf16 in -> bf16/f32 out ----------------
template<int C8, bool OUTF32>
__global__ __launch_bounds__(256) void spmm_b(const int* __restrict__ rp,
                                              const int* __restrict__ ci,
                                              const float* __restrict__ cw,
                                              const __bf16* __restrict__ h,
                                              void* __restrict__ outp) {
    constexpr int C = C8 * 8;
    constexpr int RPB = 256 / C8;
    const int r = blockIdx.x * RPB + threadIdx.x / C8;
    const int l = threadIdx.x % C8;
    if (r >= N_NODES) return;
    const bf16x8* __restrict__ h8 = (const bf16x8*)h;
    const int e0 = rp[r], e1 = rp[r + 1];
    float acc0[8] = {}, acc1[8] = {};
    int e = e0;
    for (; e + 4 <= e1; e += 4) {
        int s0 = ci[e], s1 = ci[e + 1], s2 = ci[e + 2], s3 = ci[e + 3];
        float w0 = cw[e], w1 = cw[e + 1], w2 = cw[e + 2], w3 = cw[e + 3];
        bf16x8 v0 = h8[(long)s0 * C8 + l];
        bf16x8 v1 = h8[(long)s1 * C8 + l];
        bf16x8 v2 = h8[(long)s2 * C8 + l];
        bf16x8 v3 = h8[(long)s3 * C8 + l];
        #pragma unroll
        for (int j = 0; j < 8; ++j) {
            acc0[j] = fmaf(w0, (float)v0[j], acc0[j]);
            acc1[j] = fmaf(w1, (float)v1[j], acc1[j]);
            acc0[j] = fmaf(w2, (float)v2[j], acc0[j]);
            acc1[j] = fmaf(w3, (float)v3[j], acc1[j]);
        }
    }
    for (; e < e1; ++e) {
        int s0 = ci[e]; float w0 = cw[e];
        bf16x8 v0 = h8[(long)s0 * C8 + l];
        #pragma unroll
        for (int j = 0; j < 8; ++j) acc0[j] = fmaf(w0, (float)v0[j], acc0[j]);
    }
    if (OUTF32) {
        float* o = (float*)outp + (long)r * C + l * 8;
        float4 r0 = make_float4(acc0[0] + acc1[0], acc0[1] + acc1[1], acc0[2] + acc1[2], acc0[3] + acc1[3]);
        float4 r1 = make_float4(acc0[4] + acc1[4], acc0[5] + acc1[5], acc0[6] + acc1[6], acc0[7] + acc1[7]);
        ((float4*)o)[0] = r0; ((float4*)o)[1] = r1;
    } else {
        bf16x8 res;
        #pragma unroll
        for (int j = 0; j < 8; ++j) res[j] = (__bf16)(acc0[j] + acc1[j]);
        ((bf16x8*)outp)[(long)r * C8 + l] = res;
    }
}

// ---------------- bf16 MFMA GEMM ----------------
template<int K>
__global__ __launch_bounds__(256) void gemm_mfma(const __bf16* __restrict__ A,
                                                 const __bf16* __restrict__ W,
                                                 __bf16* __restrict__ C,
                                                 int M, int Nc) {
    const int tid = threadIdx.x;
    const int wave = tid >> 6, lane = tid & 63;
    const int ln15 = lane & 15, kg = lane >> 4;
    const int m0 = blockIdx.x * 64;
    const int n0 = blockIdx.y * 64 + wave * 16;
    f32x4 acc[4];
    #pragma unroll
    for (int i = 0; i < 4; ++i) acc[i] = (f32x4){0.f, 0.f, 0.f, 0.f};

    int mrow[4];
    #pragma unroll
    for (int i = 0; i < 4; ++i) {
        int m = m0 + i * 16 + ln15;
        mrow[i] = m < M ? m : M - 1;
    }
    const __bf16* wptr = W + (long)(n0 + ln15) * K + kg * 8;
    for (int kk = 0; kk < K; kk += 32) {
        bf16x8 b = *(const bf16x8*)(wptr + kk);
        #pragma unroll
        for (int i = 0; i < 4; ++i) {
            bf16x8 a = *(const bf16x8*)(A + (long)mrow[i] * K + kk + kg * 8);
            acc[i] = __builtin_amdgcn_mfma_f32_16x16x32_bf16(a, b, acc[i], 0, 0, 0);
        }
    }
    #pragma unroll
    for (int i = 0; i < 4; ++i) {
        #pragma unroll
        for (int j = 0; j < 4; ++j) {
            int r = m0 + i * 16 + kg * 4 + j;
            if (r < M) C[(long)r * Nc + n0 + ln15] = (__bf16)acc[i][j];
        }
    }
}

// ---------------- BN stats: per-block partial sums (atomic-free) ----------------
#define NB_STATS 128
template<int C, bool BF16>
__global__ __launch_bounds__(256) void bn_stats(const void* __restrict__ hp,
                                                float* __restrict__ partial) {
    constexpr int LPR = C / 4;
    constexpr int RPI = 256 / LPR;
    const int chunk = threadIdx.x % LPR;
    const int rof   = threadIdx.x / LPR;
    float s[4] = {}, s2[4] = {};
    for (int r = blockIdx.x * RPI + rof; r < N_NODES; r += NB_STATS * RPI) {
        float v[4];
        if (BF16) {
            bf16x4 x = ((const bf16x4*)hp)[(long)r * LPR + chunk];
            #pragma unroll
            for (int j = 0; j < 4; ++j) v[j] = (float)x[j];
        } else {
            float4 x = ((const float4*)hp)[(long)r * LPR + chunk];
            v[0] = x.x; v[1] = x.y; v[2] = x.z; v[3] = x.w;
        }
        #pragma unroll
        for (int j = 0; j < 4; ++j) { s[j] += v[j]; s2[j] += v[j] * v[j]; }
    }
    __shared__ float red[256 * 8];
    #pragma unroll
    for (int j = 0; j < 4; ++j) { red[threadIdx.x * 8 + j] = s[j]; red[threadIdx.x * 8 + 4 + j] = s2[j]; }
    __syncthreads();
    if (rof == 0) {
        #pragma unroll
        for (int g = 1; g < RPI; ++g) {
            #pragma unroll
            for (int j = 0; j < 4; ++j) {
                s[j]  += red[(g * LPR + chunk) * 8 + j];
                s2[j] += red[(g * LPR + chunk) * 8 + 4 + j];
            }
        }
        #pragma unroll
        for (int j = 0; j < 4; ++j) {
            partial[blockIdx.x * 2 * C + chunk * 4 + j]     = s[j];
            partial[blockIdx.x * 2 * C + C + chunk * 4 + j] = s2[j];
        }
    }
}

// ---------------- reduce partials -> per-column scale/shift ----------------
template<int C>
__global__ void bn_reduce(const float* __restrict__ partial, const float* __restrict__ g,
                          const float* __restrict__ be, float* __restrict__ ss) {
    int c = threadIdx.x;
    float s_0 = 0.f, s_1 = 0.f, q_0 = 0.f, q_1 = 0.f;
    #pragma unroll 4
    for (int b = 0; b < NB_STATS; b += 2) {
        s_0 += partial[b * 2 * C + c];
        q_0 += partial[b * 2 * C + C + c];
        s_1 += partial[(b + 1) * 2 * C + c];
        q_1 += partial[(b + 1) * 2 * C + C + c];
    }
    float s = s_0 + s_1, s2 = q_0 + q_1;
    const float invn = 1.0f / (float)N_NODES;
    float mean = s * invn;
    float var  = s2 * invn - mean * mean;
    float rstd = rsqrtf(var + EPSV);
    float sc = g[c] * rstd;
    ss[c] = sc;
    ss[C + c] = be[c] - mean * sc;
}

// ---------------- BN apply (+leaky), vectorized ----------------
template<int C, bool RELU, bool INF32, bool OUTF32>
__global__ __launch_bounds__(256) void bn_apply(const void* __restrict__ in,
                                                void* __restrict__ outp,
                                                const float* __restrict__ ss) {
    constexpr int LPR = C / 4;
    const long total = (long)N_NODES * LPR;
    const long stride = (long)gridDim.x * blockDim.x;
    for (long idx = (long)blockIdx.x * blockDim.x + threadIdx.x; idx < total; idx += stride) {
        int chunk = (int)(idx % LPR);
        float4 sc = ((const float4*)ss)[chunk];
        float4 sh = ((const float4*)(ss + C))[chunk];
        float v[4];
        if (INF32) {
            float4 x = ((const float4*)in)[idx];
            v[0] = x.x; v[1] = x.y; v[2] = x.z; v[3] = x.w;
        } else {
            bf16x4 x = ((const bf16x4*)in)[idx];
            #pragma unroll
            for (int j = 0; j < 4; ++j) v[j] = (float)x[j];
        }
        v[0] = fmaf(v[0], sc.x, sh.x); v[1] = fmaf(v[1], sc.y, sh.y);
        v[2] = fmaf(v[2], sc.z, sh.z); v[3] = fmaf(v[3], sc.w, sh.w);
        if (RELU) {
            #pragma unroll
            for (int j = 0; j < 4; ++j) v[j] = v[j] > 0.f ? v[j] : SLOPE * v[j];
        }
        if (OUTF32) {
            ((float4*)outp)[idx] = make_float4(v[0], v[1], v[2], v[3]);
        } else {
            bf16x4 o;
            #pragma unroll
            for (int j = 0; j < 4; ++j) o[j] = (__bf16)v[j];
            ((bf16x4*)outp)[idx] = o;
        }
    }
}

extern "C" void kernel_launch(void* const* d_in, const int* in_sizes, int n_in,
                              void* d_out, int out_size, void* d_ws, size_t ws_size,
                              hipStream_t stream) {
    const float* x   = (const float*)d_in[0];
    const int*   ei  = (const int*)  d_in[1];
    const float* W0  = (const float*)d_in[2];
    const float* g0  = (const float*)d_in[4];
    const float* be0 = (const float*)d_in[5];
    const float* W1  = (const float*)d_in[6];
    const float* g1  = (const float*)d_in[8];
    const float* be1 = (const float*)d_in[9];
    const float* W2  = (const float*)d_in[10];
    const float* g2  = (const float*)d_in[12];
    const float* be2 = (const float*)d_in[13];
    float* out = (float*)d_out;

    char* wsb = (char*)d_ws;
    auto alloc = [&](size_t bytes) { char* p = wsb; wsb += (bytes + 255) & ~255UL; return p; };
    int*    deg     = (int*)   alloc(N_NODES * 4);
    int*    rp      = (int*)   alloc((N_NODES + 4) * 4);
    int*    cursor  = (int*)   alloc(N_NODES * 4);
    float*  dinv    = (float*) alloc(N_NODES * 4);
    int*    bsum    = (int*)   alloc(256 * 4);
    int*    boffs   = (int*)   alloc(257 * 4);
    float*  partial = (float*) alloc(NB_STATS * 2 * DH * 4);
    float*  ss      = (float*) alloc(2 * DH * 4);
    int*    csr_src = (int*)   alloc((N_EDGES + N_NODES) * 4);
    float*  csr_w   = (float*) alloc((N_EDGES + N_NODES) * 4);
    __bf16* w0b     = (__bf16*)alloc(DH * DIN * 2);
    __bf16* w1b     = (__bf16*)alloc(DH * DH * 2);
    __bf16* w2b     = (__bf16*)alloc(DOUT * DH * 2);
    __bf16* bf0     = (__bf16*)alloc((size_t)N_NODES * DH * 2);
    __bf16* bf1     = (__bf16*)alloc((size_t)N_NODES * DH * 2);

    // ---- weights -> bf16 ----
    cast_kernel<<<(DH * DIN / 4 + 255) / 256, 256, 0, stream>>>(W0, w0b, DH * DIN / 4);
    cast_kernel<<<(DH * DH  / 4 + 255) / 256, 256, 0, stream>>>(W1, w1b, DH * DH / 4);
    cast_kernel<<<(DOUT * DH / 4 + 255) / 256, 256, 0, stream>>>(W2, w2b, DOUT * DH / 4);

    // ---- CSR build ----
    hipMemsetAsync(deg, 0, N_NODES * 4, stream);
    hipMemsetAsync(cursor, 0, N_NODES * 4, stream);
    deg_kernel<<<(N_EDGES + 255) / 256, 256, 0, stream>>>(ei + N_EDGES, deg);
    dinv_kernel<<<(N_NODES + 255) / 256, 256, 0, stream>>>(deg, dinv);
    scan_bsum<<<SCAN_NB, 256, 0, stream>>>(deg, bsum);
    scan_boffs<<<1, 256, 0, stream>>>(bsum, boffs);
    scan_write<<<SCAN_NB, 256, 0, stream>>>(deg, boffs, rp);
    scatter_kernel<<<(N_EDGES + N_NODES + 255) / 256, 256, 0, stream>>>(
        ei, dinv, rp, cursor, csr_src, csr_w);

    // ---- layer 0: aggregate x first (A(XW^T) = (AX)W^T), DIN=128 ----
    spmm_f2b<DIN / 4><<<(N_NODES + 7) / 8, 256, 0, stream>>>(rp, csr_src, csr_w, x, bf0);
    gemm_mfma<DIN><<<dim3((N_NODES + 63) / 64, DH / 64), 256, 0, stream>>>(bf0, w0b, bf1, N_NODES, DH);
    bn_stats<DH, true><<<NB_STATS, 256, 0, stream>>>(bf1, partial);
    bn_reduce<DH><<<1, DH, 0, stream>>>(partial, g0, be0, ss);
    bn_apply<DH, true, false, false><<<2048, 256, 0, stream>>>(bf1, bf1, ss);

    // ---- layer 1 ----
    gemm_mfma<DH><<<dim3((N_NODES + 63) / 64, DH / 64), 256, 0, stream>>>(bf1, w1b, bf0, N_NODES, DH);
    spmm_b<DH / 8, false><<<(N_NODES + 7) / 8, 256, 0, stream>>>(rp, csr_src, csr_w, bf0, bf1);
    bn_stats<DH, true><<<NB_STATS, 256, 0, stream>>>(bf1, partial);
    bn_reduce<DH><<<1, DH, 0, stream>>>(partial, g1, be1, ss);
    bn_apply<DH, true, false, false><<<2048, 256, 0, stream>>>(bf1, bf1, ss);

    // ---- layer 2 ----
    gemm_mfma<DH><<<dim3((N_NODES + 63) / 64, DOUT / 64), 256, 0, stream>>>(bf1, w2b, bf0, N_NODES, DOUT);
    spmm_b<DOUT / 8, true><<<(N_NODES + 15) / 16, 256, 0, stream>>>(rp, csr_src, csr_w, bf0, out);
    bn_stats<DOUT, false><<<NB_STATS, 256, 0, stream>>>(out, partial);
    bn_reduce<DOUT><<<1, DOUT, 0, stream>>>(partial, g2, be2, ss);
    bn_apply<DOUT, false, true, true><<<2048, 256, 0, stream>>>(out, out, ss);
}

// Round 5
// 422.744 us; speedup vs baseline: 18.3571x; 1.2264x over previous
//
#include <hip/hip_runtime.h>
#include <hip/hip_bf16.h>

#define N_NODES 50000
#define N_EDGES 800000
#define DIN 128
#define DH   256
#define DOUT 128
#define EPSV 1e-5f
#define SLOPE 0.01f
#define SCAN_NB ((N_NODES + 255) / 256)   // 196

typedef __bf16 bf16x8 __attribute__((ext_vector_type(8)));
typedef __bf16 bf16x4 __attribute__((ext_vector_type(4)));
typedef float  f32x4  __attribute__((ext_vector_type(4)));

// ---------------- weight cast f32 -> bf16 ----------------
__global__ void cast_kernel(const float* __restrict__ src, __bf16* __restrict__ dst, int n4) {
    int i = blockIdx.x * blockDim.x + threadIdx.x;
    if (i < n4) {
        float4 v = ((const float4*)src)[i];
        bf16x4 o; o[0] = (__bf16)v.x; o[1] = (__bf16)v.y; o[2] = (__bf16)v.z; o[3] = (__bf16)v.w;
        ((bf16x4*)dst)[i] = o;
    }
}

// ---------------- CSR build ----------------
__global__ void deg_kernel(const int* __restrict__ dst, int* __restrict__ deg) {
    int i = blockIdx.x * blockDim.x + threadIdx.x;
    if (i < N_EDGES) atomicAdd(&deg[dst[i]], 1);
}

__global__ void dinv_kernel(const int* __restrict__ deg, float* __restrict__ dinv) {
    int i = blockIdx.x * blockDim.x + threadIdx.x;
    if (i < N_NODES) dinv[i] = rsqrtf((float)deg[i] + 1.0f);  // +1 self-loop
}

__global__ __launch_bounds__(256) void scan_bsum(const int* __restrict__ deg,
                                                 int* __restrict__ bsum) {
    __shared__ int lds[256];
    int i = blockIdx.x * 256 + threadIdx.x;
    lds[threadIdx.x] = (i < N_NODES) ? deg[i] + 1 : 0;
    __syncthreads();
    #pragma unroll
    for (int off = 128; off > 0; off >>= 1) {
        if (threadIdx.x < off) lds[threadIdx.x] += lds[threadIdx.x + off];
        __syncthreads();
    }
    if (threadIdx.x == 0) bsum[blockIdx.x] = lds[0];
}

__global__ __launch_bounds__(256) void scan_boffs(const int* __restrict__ bsum,
                                                  int* __restrict__ boffs) {
    __shared__ int lds[256];
    const int t = threadIdx.x;
    lds[t] = (t < SCAN_NB) ? bsum[t] : 0;
    __syncthreads();
    #pragma unroll
    for (int off = 1; off < 256; off <<= 1) {
        int add = (t >= off) ? lds[t - off] : 0;
        __syncthreads();
        lds[t] += add;
        __syncthreads();
    }
    boffs[t] = (t == 0) ? 0 : lds[t - 1];   // exclusive
}

__global__ __launch_bounds__(256) void scan_write(const int* __restrict__ deg,
                                                  const int* __restrict__ boffs,
                                                  int* __restrict__ rp) {
    __shared__ int lds[256];
    const int t = threadIdx.x;
    int i = blockIdx.x * 256 + t;
    int v = (i < N_NODES) ? deg[i] + 1 : 0;
    lds[t] = v;
    __syncthreads();
    #pragma unroll
    for (int off = 1; off < 256; off <<= 1) {
        int add = (t >= off) ? lds[t - off] : 0;
        __syncthreads();
        lds[t] += add;
        __syncthreads();
    }
    if (i < N_NODES) rp[i] = boffs[blockIdx.x] + lds[t] - v;
    if (i == N_NODES - 1) rp[N_NODES] = boffs[blockIdx.x] + lds[t];
}

// one 8B store per edge: (src, weight-bits)
__global__ void scatter_kernel(const int* __restrict__ ei, const float* __restrict__ dinv,
                               const int* __restrict__ rp, int* __restrict__ cursor,
                               int2* __restrict__ csr) {
    int e = blockIdx.x * blockDim.x + threadIdx.x;
    if (e >= N_EDGES + N_NODES) return;
    int src, dst; float w;
    if (e < N_EDGES) {
        src = ei[e]; dst = ei[N_EDGES + e];
        w = dinv[src] * dinv[dst];
    } else {
        src = dst = e - N_EDGES;
        w = dinv[src] * dinv[src];
    }
    int pos = rp[dst] + atomicAdd(&cursor[dst], 1);
    csr[pos] = make_int2(src, __float_as_int(w));
}

// ---------------- SpMM: f32 in -> bf16 out (layer 0, C=128) ----------------
template<int C4>
__global__ __launch_bounds__(256) void spmm_f2b(const int* __restrict__ rp,
                                                const int2* __restrict__ csr,
                                                const float* __restrict__ h,
                                                __bf16* __restrict__ out) {
    constexpr int RPB = 256 / C4;
    const int r = blockIdx.x * RPB + threadIdx.x / C4;
    const int l = threadIdx.x % C4;
    if (r >= N_NODES) return;
    const float4* __restrict__ h4 = (const float4*)h;
    const int e0 = rp[r], e1 = rp[r + 1];
    f32x4 a0 = {0.f, 0.f, 0.f, 0.f}, a1 = {0.f, 0.f, 0.f, 0.f};
    int e = e0;
    for (; e + 4 <= e1; e += 4) {
        int2 p0 = csr[e], p1 = csr[e + 1], p2 = csr[e + 2], p3 = csr[e + 3];
        float w0 = __int_as_float(p0.y), w1 = __int_as_float(p1.y);
        float w2 = __int_as_float(p2.y), w3 = __int_as_float(p3.y);
        float4 v0 = h4[(long)p0.x * C4 + l];
        float4 v1 = h4[(long)p1.x * C4 + l];
        float4 v2 = h4[(long)p2.x * C4 + l];
        float4 v3 = h4[(long)p3.x * C4 + l];
        a0[0] = fmaf(w0, v0.x, a0[0]); a0[1] = fmaf(w0, v0.y, a0[1]);
        a0[2] = fmaf(w0, v0.z, a0[2]); a0[3] = fmaf(w0, v0.w, a0[3]);
        a1[0] = fmaf(w1, v1.x, a1[0]); a1[1] = fmaf(w1, v1.y, a1[1]);
        a1[2] = fmaf(w1, v1.z, a1[2]); a1[3] = fmaf(w1, v1.w, a1[3]);
        a0[0] = fmaf(w2, v2.x, a0[0]); a0[1] = fmaf(w2, v2.y, a0[1]);
        a0[2] = fmaf(w2, v2.z, a0[2]); a0[3] = fmaf(w2, v2.w, a0[3]);
        a1[0] = fmaf(w3, v3.x, a1[0]); a1[1] = fmaf(w3, v3.y, a1[1]);
        a1[2] = fmaf(w3, v3.z, a1[2]); a1[3] = fmaf(w3, v3.w, a1[3]);
    }
    for (; e < e1; ++e) {
        int2 p0 = csr[e];
        float w0 = __int_as_float(p0.y);
        float4 v0 = h4[(long)p0.x * C4 + l];
        a0[0] = fmaf(w0, v0.x, a0[0]); a0[1] = fmaf(w0, v0.y, a0[1]);
        a0[2] = fmaf(w0, v0.z, a0[2]); a0[3] = fmaf(w0, v0.w, a0[3]);
    }
    bf16x4 res;
    #pragma unroll
    for (int j = 0; j < 4; ++j) res[j] = (__bf16)(a0[j] + a1[j]);
    ((bf16x4*)out)[(long)r * C4 + l] = res;
}

// ---------------- SpMM: bf16 in -> bf16/f32 out ----------------
template<int C8, bool OUTF32>
__global__ __launch_bounds__(256) void spmm_b(const int* __restrict__ rp,
                                              const int2* __restrict__ csr,
                                              const __bf16* __restrict__ h,
                                              void* __restrict__ outp) {
    constexpr int C = C8 * 8;
    constexpr int RPB = 256 / C8;
    const int r = blockIdx.x * RPB + threadIdx.x / C8;
    const int l = threadIdx.x % C8;
    if (r >= N_NODES) return;
    const bf16x8* __restrict__ h8 = (const bf16x8*)h;
    const int e0 = rp[r], e1 = rp[r + 1];
    float acc0[8] = {}, acc1[8] = {};
    int e = e0;
    for (; e + 4 <= e1; e += 4) {
        int2 p0 = csr[e], p1 = csr[e + 1], p2 = csr[e + 2], p3 = csr[e + 3];
        float w0 = __int_as_float(p0.y), w1 = __int_as_float(p1.y);
        float w2 = __int_as_float(p2.y), w3 = __int_as_float(p3.y);
        bf16x8 v0 = h8[(long)p0.x * C8 + l];
        bf16x8 v1 = h8[(long)p1.x * C8 + l];
        bf16x8 v2 = h8[(long)p2.x * C8 + l];
        bf16x8 v3 = h8[(long)p3.x * C8 + l];
        #pragma unroll
        for (int j = 0; j < 8; ++j) {
            acc0[j] = fmaf(w0, (float)v0[j], acc0[j]);
            acc1[j] = fmaf(w1, (float)v1[j], acc1[j]);
            acc0[j] = fmaf(w2, (float)v2[j], acc0[j]);
            acc1[j] = fmaf(w3, (float)v3[j], acc1[j]);
        }
    }
    for (; e < e1; ++e) {
        int2 p0 = csr[e];
        float w0 = __int_as_float(p0.y);
        bf16x8 v0 = h8[(long)p0.x * C8 + l];
        #pragma unroll
        for (int j = 0; j < 8; ++j) acc0[j] = fmaf(w0, (float)v0[j], acc0[j]);
    }
    if (OUTF32) {
        float* o = (float*)outp + (long)r * C + l * 8;
        float4 r0 = make_float4(acc0[0] + acc1[0], acc0[1] + acc1[1], acc0[2] + acc1[2], acc0[3] + acc1[3]);
        float4 r1 = make_float4(acc0[4] + acc1[4], acc0[5] + acc1[5], acc0[6] + acc1[6], acc0[7] + acc1[7]);
        ((float4*)o)[0] = r0; ((float4*)o)[1] = r1;
    } else {
        bf16x8 res;
        #pragma unroll
        for (int j = 0; j < 8; ++j) res[j] = (__bf16)(acc0[j] + acc1[j]);
        ((bf16x8*)outp)[(long)r * C8 + l] = res;
    }
}

// ---------------- bf16 MFMA GEMM with LDS-staged A and optional fused BN+leaky on A ----
// C[M x NC] = act(BN(A))[M x K] @ W[NC x K]^T ; 4 waves; wave tile 64x64
template<int K, int NC, bool FUSE_BN, bool RELU>
__global__ __launch_bounds__(256) void gemm_tile(const __bf16* __restrict__ A,
                                                 const __bf16* __restrict__ W,
                                                 const float* __restrict__ ss,
                                                 __bf16* __restrict__ C,
                                                 int M) {
    constexpr int NW = NC / 64;           // waves along N (4 for 256, 2 for 128)
    constexpr int MW = 4 / NW;            // waves along M (1 or 2)
    constexpr int BM = MW * 64;           // block rows
    constexpr int LSTR = 40;              // padded LDS row stride (bf16): 80B, 16B-aligned
    __shared__ __bf16 As[BM][LSTR];

    const int tid = threadIdx.x;
    const int wave = tid >> 6, lane = tid & 63;
    const int ln15 = lane & 15, kg = lane >> 4;
    const int wm = wave / NW, wn = wave % NW;
    const int m0 = blockIdx.x * BM;

    const int srow = tid >> 2;            // staging row 0..63
    const int schunk = tid & 3;           // staging chunk (8 bf16)

    f32x4 acc[4][4];
    #pragma unroll
    for (int i = 0; i < 4; ++i)
        #pragma unroll
        for (int j = 0; j < 4; ++j) acc[i][j] = (f32x4){0.f, 0.f, 0.f, 0.f};

    for (int kt = 0; kt < K; kt += 32) {
        // ---- stage A[BM][32] into LDS (BN+leaky fused if requested) ----
        #pragma unroll
        for (int p = 0; p < MW; ++p) {
            int gr = m0 + p * 64 + srow;
            gr = gr < M ? gr : M - 1;
            bf16x8 v = *(const bf16x8*)(A + (long)gr * K + kt + schunk * 8);
            if (FUSE_BN) {
                const f32x4* ss4 = (const f32x4*)ss;
                int ci = (kt + schunk * 8) >> 2;
                f32x4 sc0 = ss4[ci],            sc1 = ss4[ci + 1];
                f32x4 sh0 = ss4[(K >> 2) + ci], sh1 = ss4[(K >> 2) + ci + 1];
                float f[8];
                #pragma unroll
                for (int j = 0; j < 4; ++j) {
                    f[j]     = fmaf((float)v[j],     sc0[j], sh0[j]);
                    f[j + 4] = fmaf((float)v[j + 4], sc1[j], sh1[j]);
                }
                if (RELU) {
                    #pragma unroll
                    for (int j = 0; j < 8; ++j) f[j] = f[j] > 0.f ? f[j] : SLOPE * f[j];
                }
                #pragma unroll
                for (int j = 0; j < 8; ++j) v[j] = (__bf16)f[j];
            }
            *(bf16x8*)(&As[p * 64 + srow][schunk * 8]) = v;
        }
        __syncthreads();
        // ---- B fragments (W is small, L2-resident) ----
        bf16x8 b[4];
        #pragma unroll
        for (int j = 0; j < 4; ++j)
            b[j] = *(const bf16x8*)(W + (long)(wn * 64 + j * 16 + ln15) * K + kt + kg * 8);
        // ---- A fragments from LDS + MFMA, 4x reuse each side ----
        #pragma unroll
        for (int i = 0; i < 4; ++i) {
            bf16x8 a = *(const bf16x8*)(&As[wm * 64 + i * 16 + ln15][kg * 8]);
            #pragma unroll
            for (int j = 0; j < 4; ++j)
                acc[i][j] = __builtin_amdgcn_mfma_f32_16x16x32_bf16(a, b[j], acc[i][j], 0, 0, 0);
        }
        __syncthreads();
    }
    // ---- store ----
    #pragma unroll
    for (int i = 0; i < 4; ++i) {
        #pragma unroll
        for (int j = 0; j < 4; ++j) {
            #pragma unroll
            for (int q = 0; q < 4; ++q) {
                int r = m0 + wm * 64 + i * 16 + kg * 4 + q;
                if (r < M) C[(long)r * NC + wn * 64 + j * 16 + ln15] = (__bf16)acc[i][j][q];
            }
        }
    }
}

// ---------------- BN stats: per-block partial sums (atomic-free) ----------------
#define NB_STATS 128
template<int C, bool BF16>
__global__ __launch_bounds__(256) void bn_stats(const void* __restrict__ hp,
                                                float* __restrict__ partial) {
    constexpr int LPR = C / 4;
    constexpr int RPI = 256 / LPR;
    const int chunk = threadIdx.x % LPR;
    const int rof   = threadIdx.x / LPR;
    float s[4] = {}, s2[4] = {};
    for (int r = blockIdx.x * RPI + rof; r < N_NODES; r += NB_STATS * RPI) {
        float v[4];
        if (BF16) {
            bf16x4 x = ((const bf16x4*)hp)[(long)r * LPR + chunk];
            #pragma unroll
            for (int j = 0; j < 4; ++j) v[j] = (float)x[j];
        } else {
            float4 x = ((const float4*)hp)[(long)r * LPR + chunk];
            v[0] = x.x; v[1] = x.y; v[2] = x.z; v[3] = x.w;
        }
        #pragma unroll
        for (int j = 0; j < 4; ++j) { s[j] += v[j]; s2[j] += v[j] * v[j]; }
    }
    __shared__ float red[256 * 8];
    #pragma unroll
    for (int j = 0; j < 4; ++j) { red[threadIdx.x * 8 + j] = s[j]; red[threadIdx.x * 8 + 4 + j] = s2[j]; }
    __syncthreads();
    if (rof == 0) {
        #pragma unroll
        for (int g = 1; g < RPI; ++g) {
            #pragma unroll
            for (int j = 0; j < 4; ++j) {
                s[j]  += red[(g * LPR + chunk) * 8 + j];
                s2[j] += red[(g * LPR + chunk) * 8 + 4 + j];
            }
        }
        #pragma unroll
        for (int j = 0; j < 4; ++j) {
            partial[blockIdx.x * 2 * C + chunk * 4 + j]     = s[j];
            partial[blockIdx.x * 2 * C + C + chunk * 4 + j] = s2[j];
        }
    }
}

// ---------------- reduce partials -> per-column scale/shift ----------------
template<int C>
__global__ void bn_reduce(const float* __restrict__ partial, const float* __restrict__ g,
                          const float* __restrict__ be, float* __restrict__ ss) {
    int c = threadIdx.x;
    float s_0 = 0.f, s_1 = 0.f, q_0 = 0.f, q_1 = 0.f;
    #pragma unroll 4
    for (int b = 0; b < NB_STATS; b += 2) {
        s_0 += partial[b * 2 * C + c];
        q_0 += partial[b * 2 * C + C + c];
        s_1 += partial[(b + 1) * 2 * C + c];
        q_1 += partial[(b + 1) * 2 * C + C + c];
    }
    float s = s_0 + s_1, s2 = q_0 + q_1;
    const float invn = 1.0f / (float)N_NODES;
    float mean = s * invn;
    float var  = s2 * invn - mean * mean;
    float rstd = rsqrtf(var + EPSV);
    float sc = g[c] * rstd;
    ss[c] = sc;
    ss[C + c] = be[c] - mean * sc;
}

// ---------------- BN apply (final layer only, f32 in-place) ----------------
template<int C, bool RELU, bool INF32, bool OUTF32>
__global__ __launch_bounds__(256) void bn_apply(const void* __restrict__ in,
                                                void* __restrict__ outp,
                                                const float* __restrict__ ss) {
    constexpr int LPR = C / 4;
    const long total = (long)N_NODES * LPR;
    const long stride = (long)gridDim.x * blockDim.x;
    for (long idx = (long)blockIdx.x * blockDim.x + threadIdx.x; idx < total; idx += stride) {
        int chunk = (int)(idx % LPR);
        float4 sc = ((const float4*)ss)[chunk];
        float4 sh = ((const float4*)(ss + C))[chunk];
        float v[4];
        if (INF32) {
            float4 x = ((const float4*)in)[idx];
            v[0] = x.x; v[1] = x.y; v[2] = x.z; v[3] = x.w;
        } else {
            bf16x4 x = ((const bf16x4*)in)[idx];
            #pragma unroll
            for (int j = 0; j < 4; ++j) v[j] = (float)x[j];
        }
        v[0] = fmaf(v[0], sc.x, sh.x); v[1] = fmaf(v[1], sc.y, sh.y);
        v[2] = fmaf(v[2], sc.z, sh.z); v[3] = fmaf(v[3], sc.w, sh.w);
        if (RELU) {
            #pragma unroll
            for (int j = 0; j < 4; ++j) v[j] = v[j] > 0.f ? v[j] : SLOPE * v[j];
        }
        if (OUTF32) {
            ((float4*)outp)[idx] = make_float4(v[0], v[1], v[2], v[3]);
        } else {
            bf16x4 o;
            #pragma unroll
            for (int j = 0; j < 4; ++j) o[j] = (__bf16)v[j];
            ((bf16x4*)outp)[idx] = o;
        }
    }
}

extern "C" void kernel_launch(void* const* d_in, const int* in_sizes, int n_in,
                              void* d_out, int out_size, void* d_ws, size_t ws_size,
                              hipStream_t stream) {
    const float* x   = (const float*)d_in[0];
    const int*   ei  = (const int*)  d_in[1];
    const float* W0  = (const float*)d_in[2];
    const float* g0  = (const float*)d_in[4];
    const float* be0 = (const float*)d_in[5];
    const float* W1  = (const float*)d_in[6];
    const float* g1  = (const float*)d_in[8];
    const float* be1 = (const float*)d_in[9];
    const float* W2  = (const float*)d_in[10];
    const float* g2  = (const float*)d_in[12];
    const float* be2 = (const float*)d_in[13];
    float* out = (float*)d_out;

    char* wsb = (char*)d_ws;
    auto alloc = [&](size_t bytes) { char* p = wsb; wsb += (bytes + 255) & ~255UL; return p; };
    int*    deg     = (int*)   alloc(N_NODES * 4);
    int*    rp      = (int*)   alloc((N_NODES + 4) * 4);
    int*    cursor  = (int*)   alloc(N_NODES * 4);
    float*  dinv    = (float*) alloc(N_NODES * 4);
    int*    bsum    = (int*)   alloc(256 * 4);
    int*    boffs   = (int*)   alloc(257 * 4);
    float*  partial = (float*) alloc(NB_STATS * 2 * DH * 4);
    float*  ss      = (float*) alloc(2 * DH * 4);
    int2*   csr     = (int2*)  alloc((size_t)(N_EDGES + N_NODES) * 8);
    __bf16* w0b     = (__bf16*)alloc(DH * DIN * 2);
    __bf16* w1b     = (__bf16*)alloc(DH * DH * 2);
    __bf16* w2b     = (__bf16*)alloc(DOUT * DH * 2);
    __bf16* bf0     = (__bf16*)alloc((size_t)N_NODES * DH * 2);
    __bf16* bf1     = (__bf16*)alloc((size_t)N_NODES * DH * 2);

    // ---- weights -> bf16 ----
    cast_kernel<<<(DH * DIN / 4 + 255) / 256, 256, 0, stream>>>(W0, w0b, DH * DIN / 4);
    cast_kernel<<<(DH * DH  / 4 + 255) / 256, 256, 0, stream>>>(W1, w1b, DH * DH / 4);
    cast_kernel<<<(DOUT * DH / 4 + 255) / 256, 256, 0, stream>>>(W2, w2b, DOUT * DH / 4);

    // ---- CSR build ----
    hipMemsetAsync(deg, 0, N_NODES * 4, stream);
    hipMemsetAsync(cursor, 0, N_NODES * 4, stream);
    deg_kernel<<<(N_EDGES + 255) / 256, 256, 0, stream>>>(ei + N_EDGES, deg);
    dinv_kernel<<<(N_NODES + 255) / 256, 256, 0, stream>>>(deg, dinv);
    scan_bsum<<<SCAN_NB, 256, 0, stream>>>(deg, bsum);
    scan_boffs<<<1, 256, 0, stream>>>(bsum, boffs);
    scan_write<<<SCAN_NB, 256, 0, stream>>>(deg, boffs, rp);
    scatter_kernel<<<(N_EDGES + N_NODES + 255) / 256, 256, 0, stream>>>(
        ei, dinv, rp, cursor, csr);

    // ---- layer 0: aggregate x first (A(XW^T) = (AX)W^T), then GEMM ----
    spmm_f2b<DIN / 4><<<(N_NODES + 7) / 8, 256, 0, stream>>>(rp, csr, x, bf0);
    gemm_tile<DIN, DH, false, false><<<(N_NODES + 63) / 64, 256, 0, stream>>>(
        bf0, w0b, nullptr, bf1, N_NODES);
    bn_stats<DH, true><<<NB_STATS, 256, 0, stream>>>(bf1, partial);
    bn_reduce<DH><<<1, DH, 0, stream>>>(partial, g0, be0, ss);

    // ---- layer 1: gemm reads bf1 with fused BN0+leaky; then aggregate ----
    gemm_tile<DH, DH, true, true><<<(N_NODES + 63) / 64, 256, 0, stream>>>(
        bf1, w1b, ss, bf0, N_NODES);
    spmm_b<DH / 8, false><<<(N_NODES + 7) / 8, 256, 0, stream>>>(rp, csr, bf0, bf1);
    bn_stats<DH, true><<<NB_STATS, 256, 0, stream>>>(bf1, partial);
    bn_reduce<DH><<<1, DH, 0, stream>>>(partial, g1, be1, ss);

    // ---- layer 2: gemm reads bf1 with fused BN1+leaky; aggregate -> out; final BN ----
    gemm_tile<DH, DOUT, true, true><<<(N_NODES + 127) / 128, 256, 0, stream>>>(
        bf1, w2b, ss, bf0, N_NODES);
    spmm_b<DOUT / 8, true><<<(N_NODES + 15) / 16, 256, 0, stream>>>(rp, csr, bf0, out);
    bn_stats<DOUT, false><<<NB_STATS, 256, 0, stream>>>(out, partial);
    bn_reduce<DOUT><<<1, DOUT, 0, stream>>>(partial, g2, be2, ss);
    bn_apply<DOUT, false, true, true><<<2048, 256, 0, stream>>>(out, out, ss);
}